// Round 13
// baseline (548.102 us; speedup 1.0000x reference)
//
#include <hip/hip_runtime.h>
#include <hip/hip_fp16.h>

// Problem constants (fixed by the reference)
constexpr int Bb = 32;     // batch
constexpr int Tt = 32;     // time steps
constexpr int Ii = 8192;   // input dim
constexpr int Hh = 8192;   // hidden dim
constexpr int Oo = 2048;   // output dim
constexpr int TB = Tt * Bb;  // halves per x2 column = 1024
constexpr int TCH = 4;       // timesteps per XCD chunk
constexpr int TILE = 2048;   // COO entries per tile
constexpr int FBR = 32;      // rows per fine bucket
constexpr int NFB_H = Hh / FBR;  // 256
constexpr int NFB_O = Oo / FBR;  // 64

// Entry packing: lo16 = col (u16), hi16 = fp16 value bits. 4 B/entry.
// Rows padded to multiples of 32 entries (128 B) -> 2x int4 per quarter-wave.
//
// Journal of failed experiments (do not retry):
//  - R1: XCD row-partitioned single-pass scatter: 8x COO re-scan -> +74 MB
//    FETCH, write amp stayed (94->64 MB). Regressed 117->164 us.
//  - R2: all-32-step cooperative kernel w/ grid.sync(): ~280 us PER SYNC at
//    2048 blocks. 24x regression. Dispatch boundaries are the cheap sync.
//  - R3/R4: __builtin_nontemporal_load build -> container failed twice. Avoid.
//  - R6: partition-local bscatter: WRITE still 53.6 MB = 7.3x payload. gfx950
//    stores do NOT write-allocate in L2; random 4B stores have a ~7-8x HBM
//    write-amp floor. Dense writes only.
//  - R7: metadata scans need block-level parallelism.
//  - R8: cross-XCD contended global atomics pay HBM (L2 line ping-pong);
//    derive histograms from bucketed data.
//  - R10: preih single-pass (all 32 t per wave) = L2 thrash (402 MB, 2x
//    worse). Keep gather working sets L2-resident even at the cost of
//    redundant instruction work.
//  - R12: step 2x unroll + out quarter-split = -4.8 us only. The 32 step
//    dispatches are LAUNCH/LATENCY-bound (~6 us/step overhead), not
//    issue-bound. Further step instruction cuts are pointless; the
//    recurrence is at its structural floor for the per-dispatch scheme.

__device__ __forceinline__ float entval(uint32_t u) {
  return __half2float(__ushort_as_half((unsigned short)(u >> 16)));
}

// ---------------- x transpose: (B,T,I) fp32 -> (I,T,B) fp16 ----------------
__global__ void transpose_x_kernel(const float* __restrict__ x, __half2* __restrict__ x2) {
  int blk = blockIdx.x;          // (Tt/2) * (Ii/64) = 2048 blocks
  int tp = blk >> 7;
  int ib = blk & 127;
  int t0 = tp * 2;
  int i0 = ib * 64;
  __shared__ float lds[64][65];
  int tid = threadIdx.x;
  for (int idx = tid; idx < 64 * 64; idx += 256) {
    int row = idx >> 6, il = idx & 63;     // coalesced reads along i
    int tt = row >> 5, bb = row & 31;
    lds[il][row] = x[(size_t)bb * Tt * Ii + (size_t)(t0 + tt) * Ii + i0 + il];
  }
  __syncthreads();
  for (int idx = tid; idx < 64 * 32; idx += 256) {
    int il = idx >> 5;
    int q = idx & 31;
    int tt = q >> 4, p = q & 15;           // b-pair p -> batches 2p, 2p+1
    float lo = lds[il][tt * 32 + 2 * p];
    float hi = lds[il][tt * 32 + 2 * p + 1];
    x2[(size_t)(i0 + il) * (TB / 2) + (size_t)(t0 + tt) * 16 + p] = __floats2half2_rn(lo, hi);
  }
}

// ---------------- CSR build: dense-write counting sort ----------------
// Phase 1: per-(tile, 32-row fbucket) counts ONLY (LDS atomics, dense write).
__global__ void __launch_bounds__(256) count_kernel(
    const int* __restrict__ r1, int n1, int* __restrict__ tb1, int nt1,
    const int* __restrict__ r2, int n2, int* __restrict__ tb2, int nt2,
    const int* __restrict__ r3, int n3, int* __restrict__ tb3) {
  __shared__ int cnt[NFB_H];
  int tile = blockIdx.x;
  const int* rows; int n; int* tb; int tl; int nfb;
  if (tile < nt1)            { rows = r1; n = n1; tb = tb1; tl = tile;             nfb = NFB_H; }
  else if (tile < nt1 + nt2) { rows = r2; n = n2; tb = tb2; tl = tile - nt1;       nfb = NFB_H; }
  else                       { rows = r3; n = n3; tb = tb3; tl = tile - nt1 - nt2; nfb = NFB_O; }
  for (int i = threadIdx.x; i < nfb; i += 256) cnt[i] = 0;
  __syncthreads();
  int base = tl * TILE;
  for (int k = threadIdx.x; k < TILE; k += 256) {
    int j = base + k;
    if (j < n) atomicAdd(&cnt[rows[j] >> 5], 1);     // fine-bucket count (LDS)
  }
  __syncthreads();
  for (int i = threadIdx.x; i < nfb; i += 256) tb[tl * nfb + i] = cnt[i];
}

// Phase 2b: per-column (fbucket) exclusive scan over tiles, block-parallel.
__global__ void __launch_bounds__(256) scan_col_kernel(
    int* __restrict__ tb1, int nt1, int* __restrict__ tb2, int nt2,
    int* __restrict__ tb3, int nt3, int* __restrict__ totals) {
  __shared__ int sums[256];
  int col = blockIdx.x;
  int* tb; int nt; int fb; int nfb;
  if (col < NFB_H)          { tb = tb1; nt = nt1; fb = col;             nfb = NFB_H; }
  else if (col < 2 * NFB_H) { tb = tb2; nt = nt2; fb = col - NFB_H;     nfb = NFB_H; }
  else                      { tb = tb3; nt = nt3; fb = col - 2 * NFB_H; nfb = NFB_O; }
  int tid = threadIdx.x;
  int nper = (nt + 255) >> 8;            // <=2 at these sizes
  int vals[8];                            // slack
  int t0 = tid * nper;
  int a = 0;
  for (int i = 0; i < nper; i++) {
    int t = t0 + i;
    vals[i] = (t < nt) ? tb[t * nfb + fb] : 0;
    a += vals[i];
  }
  sums[tid] = a;
  __syncthreads();
  for (int off = 1; off < 256; off <<= 1) {
    int o = (tid >= off) ? sums[tid - off] : 0;
    __syncthreads();
    sums[tid] += o;
    __syncthreads();
  }
  int run = sums[tid] - a;
  for (int i = 0; i < nper; i++) {
    int t = t0 + i;
    if (t < nt) { tb[t * nfb + fb] = run; run += vals[i]; }
  }
  if (tid == 255) totals[col] = sums[255];
}

// Phase 2c: exclusive scan of column totals -> bucket bases fbb[nfb+1].
__global__ void __launch_bounds__(256) scan_base_kernel(
    const int* __restrict__ totals, int* __restrict__ fbb1,
    int* __restrict__ fbb2, int* __restrict__ fbb3) {
  __shared__ int s[256];
  int m = blockIdx.x;
  const int* t; int* fbb; int nfb;
  if (m == 0)      { t = totals;             fbb = fbb1; nfb = NFB_H; }
  else if (m == 1) { t = totals + NFB_H;     fbb = fbb2; nfb = NFB_H; }
  else             { t = totals + 2 * NFB_H; fbb = fbb3; nfb = NFB_O; }
  int tid = threadIdx.x;
  int v = (tid < nfb) ? t[tid] : 0;
  s[tid] = v;
  __syncthreads();
  for (int off = 1; off < 256; off <<= 1) {
    int o = (tid >= off) ? s[tid - off] : 0;
    __syncthreads();
    s[tid] += o;
    __syncthreads();
  }
  if (tid < nfb) fbb[tid] = s[tid] - v;
  if (tid == 255) fbb[nfb] = s[255];
}

// Phase 3: LDS-staged binning -> DENSE u64 stream writes (entry<<32 | row).
__global__ void __launch_bounds__(256) place_kernel(
    const int* __restrict__ r1, const int* __restrict__ c1, const float* __restrict__ v1,
    int n1, const int* __restrict__ tb1, int nt1, const int* __restrict__ fbb1, uint64_t* __restrict__ s1,
    const int* __restrict__ r2, const int* __restrict__ c2, const float* __restrict__ v2,
    int n2, const int* __restrict__ tb2, int nt2, const int* __restrict__ fbb2, uint64_t* __restrict__ s2,
    const int* __restrict__ r3, const int* __restrict__ c3, const float* __restrict__ v3,
    int n3, const int* __restrict__ tb3, const int* __restrict__ fbb3, uint64_t* __restrict__ s3) {
  __shared__ int cnt[NFB_H];
  __shared__ int incl[NFB_H];
  __shared__ uint64_t stg[TILE];
  __shared__ int gad[TILE];
  int tile = blockIdx.x;
  const int* rows; const int* cols; const float* vals; int n;
  const int* tb; const int* fbb; uint64_t* st; int tl; int nfb;
  if (tile < nt1)            { rows = r1; cols = c1; vals = v1; n = n1; tb = tb1; fbb = fbb1; st = s1; tl = tile;             nfb = NFB_H; }
  else if (tile < nt1 + nt2) { rows = r2; cols = c2; vals = v2; n = n2; tb = tb2; fbb = fbb2; st = s2; tl = tile - nt1;       nfb = NFB_H; }
  else                       { rows = r3; cols = c3; vals = v3; n = n3; tb = tb3; fbb = fbb3; st = s3; tl = tile - nt1 - nt2; nfb = NFB_O; }
  int tid = threadIdx.x;
  for (int i = tid; i < NFB_H; i += 256) cnt[i] = 0;   // zero full 256 (scan below is fixed-width)
  __syncthreads();
  constexpr int E = TILE / 256;                        // 8 entries/thread
  uint32_t entv[E]; int rowv[E]; int rnkv[E];
  int base = tl * TILE;
  for (int k = 0; k < E; k++) {
    int j = base + k * 256 + tid;
    if (j < n) {
      int rr = rows[j];
      rowv[k] = rr;
      entv[k] = ((uint32_t)__half_as_ushort(__float2half_rn(vals[j])) << 16) | (uint32_t)cols[j];
      rnkv[k] = atomicAdd(&cnt[rr >> 5], 1);
    } else {
      rowv[k] = -1;
    }
  }
  __syncthreads();
  // inclusive scan of cnt[0..255] -> incl (Hillis-Steele)
  int v0 = cnt[tid];
  incl[tid] = v0;
  __syncthreads();
  for (int off = 1; off < 256; off <<= 1) {
    int o = (tid >= off) ? incl[tid - off] : 0;
    __syncthreads();
    incl[tid] += o;
    __syncthreads();
  }
  int total = incl[255];
  for (int k = 0; k < E; k++) {
    if (rowv[k] >= 0) {
      int fb = rowv[k] >> 5;
      int slot = (incl[fb] - cnt[fb]) + rnkv[k];       // exclusive offset + rank
      stg[slot] = ((uint64_t)entv[k] << 32) | (uint32_t)rowv[k];
      gad[slot] = fbb[fb] + tb[tl * nfb + fb] + rnkv[k];
    }
  }
  __syncthreads();
  for (int i = tid; i < total; i += 256) st[gad[i]] = stg[i];
}

// Phase 3b: per-row histogram from the bucketed stream (atomic-free global).
__global__ void __launch_bounds__(256) rowcount_kernel(
    const uint64_t* __restrict__ s1, const int* __restrict__ fbb1, int* __restrict__ cu1,
    const uint64_t* __restrict__ s2, const int* __restrict__ fbb2, int* __restrict__ cu2,
    const uint64_t* __restrict__ s3, const int* __restrict__ fbb3, int* __restrict__ cu3) {
  __shared__ int rc[FBR];
  int bx = blockIdx.x;
  const uint64_t* st; const int* fbb; int* cu; int b;
  if (bx < NFB_H)          { st = s1; fbb = fbb1; cu = cu1; b = bx; }
  else if (bx < 2 * NFB_H) { st = s2; fbb = fbb2; cu = cu2; b = bx - NFB_H; }
  else                     { st = s3; fbb = fbb3; cu = cu3; b = bx - 2 * NFB_H; }
  int tid = threadIdx.x;
  if (tid < FBR) rc[tid] = 0;
  __syncthreads();
  int lo = fbb[b], hi = fbb[b + 1];
  for (int j = lo + tid; j < hi; j += 256)
    atomicAdd(&rc[(int)(uint32_t)st[j] & (FBR - 1)], 1);
  __syncthreads();
  if (tid < FBR) cu[(b << 5) + tid] = rc[tid];
}

// Phase 2a (after rowcount): CSR exclusive scan; rows padded to 32 entries.
// rs[r]=start (32-padded), cur[r]=rs+cnt (end pointer).
__global__ void scan_csr_kernel(int* __restrict__ c1, int n1, int* __restrict__ r1,
                                int* __restrict__ c2, int n2, int* __restrict__ r2,
                                int* __restrict__ c3, int n3, int* __restrict__ r3) {
  __shared__ int sums[1024];
  int bx = blockIdx.x;
  int tid = threadIdx.x;
  int* cnt_cursor; int n; int* row_start;
  if (bx == 0)      { cnt_cursor = c1; n = n1; row_start = r1; }
  else if (bx == 1) { cnt_cursor = c2; n = n2; row_start = r2; }
  else              { cnt_cursor = c3; n = n3; row_start = r3; }
  int chunk = (n + 1023) >> 10;
  int base = tid * chunk;
  int s = 0;
  for (int i = 0; i < chunk; i++) {
    int idx = base + i;
    if (idx < n) s += (cnt_cursor[idx] + 31) & ~31;
  }
  sums[tid] = s;
  __syncthreads();
  for (int off = 1; off < 1024; off <<= 1) {
    int other = (tid >= off) ? sums[tid - off] : 0;
    __syncthreads();
    sums[tid] += other;
    __syncthreads();
  }
  int run = sums[tid] - s;
  for (int i = 0; i < chunk; i++) {
    int idx = base + i;
    if (idx < n) {
      int v = cnt_cursor[idx];
      row_start[idx] = run;
      cnt_cursor[idx] = run + v;     // end pointer (unpadded)
      run += (v + 31) & ~31;
    }
  }
  if (tid == 1023) row_start[n] = sums[1023];
}

// Phase 4: one block per 32-row fbucket: reorder into exact padded-CSR layout
// in LDS (pads zeroed), flush with fully-coalesced stores.
__global__ void __launch_bounds__(256) csort_kernel(
    const uint64_t* __restrict__ s1, const int* __restrict__ fbb1, const int* __restrict__ rs1, uint32_t* __restrict__ e1,
    const uint64_t* __restrict__ s2, const int* __restrict__ fbb2, const int* __restrict__ rs2, uint32_t* __restrict__ e2,
    const uint64_t* __restrict__ s3, const int* __restrict__ fbb3, const int* __restrict__ rs3, uint32_t* __restrict__ e3) {
  __shared__ uint32_t ob[8192];
  __shared__ int rcnt[FBR];
  __shared__ int rsl[FBR + 1];
  int bx = blockIdx.x;
  const uint64_t* st; const int* fbb; const int* rs; uint32_t* e; int b;
  if (bx < NFB_H)            { st = s1; fbb = fbb1; rs = rs1; e = e1; b = bx; }
  else if (bx < 2 * NFB_H)   { st = s2; fbb = fbb2; rs = rs2; e = e2; b = bx - NFB_H; }
  else                       { st = s3; fbb = fbb3; rs = rs3; e = e3; b = bx - 2 * NFB_H; }
  int tid = threadIdx.x;
  if (tid <= FBR) rsl[tid] = rs[(b << 5) + tid];
  if (tid < FBR) rcnt[tid] = 0;
  __syncthreads();
  int reg0 = rsl[0];
  int rlen = rsl[FBR] - reg0;
  int lo = fbb[b], hi = fbb[b + 1];
  if (rlen <= 8192) {
    for (int i = tid; i < rlen; i += 256) ob[i] = 0;
    __syncthreads();
    for (int j = lo + tid; j < hi; j += 256) {
      uint64_t v = st[j];
      int rl = (int)(uint32_t)v & (FBR - 1);
      int rk = atomicAdd(&rcnt[rl], 1);
      ob[(rsl[rl] - reg0) + rk] = (uint32_t)(v >> 32);
    }
    __syncthreads();
    for (int i = tid; i < rlen; i += 256) e[reg0 + i] = ob[i];
  } else {
    // paranoia fallback (never expected at these densities)
    for (int i = tid; i < rlen; i += 256) e[reg0 + i] = 0;
    __syncthreads();
    for (int j = lo + tid; j < hi; j += 256) {
      uint64_t v = st[j];
      int rl = (int)(uint32_t)v & (FBR - 1);
      int rk = atomicAdd(&rcnt[rl], 1);
      e[rsl[rl] + rk] = (uint32_t)(v >> 32);
    }
  }
}

// ---------------- preIH, XCD-pinned time chunks, half-wave paired gathers ----
// xcd = blockIdx&7 owns t-chunk [4*xcd, 4*xcd+4): 2 MB x2 slice L2-resident
// (unchanged memory regime). NEW (R13): entries processed in PAIRS -- lanes
// 0-31 take the even entry, lanes 32-63 the odd entry; each lane gathers a
// uint2 (2 consecutive (t,p) slots = 4 batch halves), so 32 lanes cover all
// 64 slots of one entry. Halves gather instrs + addressing vs per-entry
// full-wave uint gathers. Cross-half shfl_xor(32) reduce at epilogue.
__global__ void __launch_bounds__(256, 8) preih_kernel(
    const int* __restrict__ ih_rs, const int* __restrict__ ih_cur,
    const uint32_t* __restrict__ ih_ent,
    const float* __restrict__ hh_bias, const __half* __restrict__ x2h,
    __half2* __restrict__ preAll) {
  int xcd = blockIdx.x & 7;
  int r = ((blockIdx.x >> 3) << 2) + (threadIdx.x >> 6);
  int lane = threadIdx.x & 63;
  int hf = lane >> 5;            // entry parity within pair
  int sl = lane & 31;            // slot-pair index: uints 2sl, 2sl+1 of chunk
  int t0 = xcd * TCH;
  int s0  = __builtin_amdgcn_readfirstlane(ih_rs[r]);       // multiple of 32
  int cnt = __builtin_amdgcn_readfirstlane(ih_cur[r]) - s0;
  int nb = (cnt + 7) >> 3;                                  // 8-entry blocks
  const int4* ep = (const int4*)(ih_ent + s0);
  // uint2 view of this chunk's slice: column stride = TB/4 = 256 uint2
  const uint2* xb = (const uint2*)((const uint32_t*)x2h + (size_t)t0 * 16);

  float2 aL = {0.f, 0.f}, aH = {0.f, 0.f};
  int4 f0 = ep[0], f1 = ep[1];
  for (int i = 0; i < nb; i++) {
    int4 e0 = f0, e1 = f1;
    f0 = ep[2 * i + 2];            // prefetch next block during gathers
    f1 = ep[2 * i + 3];
    uint32_t ua0 = (uint32_t)(hf ? e0.y : e0.x);   // pair 0: entries 0,1
    uint32_t ua1 = (uint32_t)(hf ? e0.w : e0.z);   // pair 1: entries 2,3
    uint32_t ua2 = (uint32_t)(hf ? e1.y : e1.x);   // pair 2: entries 4,5
    uint32_t ua3 = (uint32_t)(hf ? e1.w : e1.z);   // pair 3: entries 6,7
    uint2 g0 = xb[(size_t)(ua0 & 0xffff) * 256 + sl];
    uint2 g1 = xb[(size_t)(ua1 & 0xffff) * 256 + sl];
    uint2 g2 = xb[(size_t)(ua2 & 0xffff) * 256 + sl];
    uint2 g3 = xb[(size_t)(ua3 & 0xffff) * 256 + sl];
    float v0 = entval(ua0), v1 = entval(ua1), v2 = entval(ua2), v3 = entval(ua3);
    float2 x0l = __half22float2(*(__half2*)&g0.x), x0h = __half22float2(*(__half2*)&g0.y);
    float2 x1l = __half22float2(*(__half2*)&g1.x), x1h = __half22float2(*(__half2*)&g1.y);
    float2 x2l = __half22float2(*(__half2*)&g2.x), x2h2 = __half22float2(*(__half2*)&g2.y);
    float2 x3l = __half22float2(*(__half2*)&g3.x), x3h = __half22float2(*(__half2*)&g3.y);
    aL.x += v0 * x0l.x;  aL.y += v0 * x0l.y;  aH.x += v0 * x0h.x;  aH.y += v0 * x0h.y;
    aL.x += v1 * x1l.x;  aL.y += v1 * x1l.y;  aH.x += v1 * x1h.x;  aH.y += v1 * x1h.y;
    aL.x += v2 * x2l.x;  aL.y += v2 * x2l.y;  aH.x += v2 * x2h2.x; aH.y += v2 * x2h2.y;
    aL.x += v3 * x3l.x;  aL.y += v3 * x3l.y;  aH.x += v3 * x3h.x;  aH.y += v3 * x3h.y;
  }
  // combine even-entry half (lanes 0-31) with odd-entry half (lanes 32-63)
  aL.x += __shfl_xor(aL.x, 32, 64);  aL.y += __shfl_xor(aL.y, 32, 64);
  aH.x += __shfl_xor(aH.x, 32, 64);  aH.y += __shfl_xor(aH.y, 32, 64);
  if (hf == 0) {
    float bias = hh_bias[r];
    int tt = sl >> 3;              // slot 2sl -> t = (2sl)>>4
    int p = (2 * sl) & 15;         // even -> uint2 store is 8B aligned
    __half2 h0 = __floats2half2_rn(aL.x + bias, aL.y + bias);
    __half2 h1 = __floats2half2_rn(aH.x + bias, aH.y + bias);
    uint2 wv;
    wv.x = *(uint32_t*)&h0;
    wv.y = *(uint32_t*)&h1;
    *(uint2*)(preAll + ((size_t)(t0 + tt) * Hh + r) * 16 + p) = wv;
  }
}

// ---------------- One recurrence step: h_{t+1} = sigmoid(pre_t + HH @ h_t) ----
// Quarter-split + 2x unroll (R12 form; latency/launch-bound, leave alone).
__global__ void __launch_bounds__(256, 8) step_kernel(
    const int* __restrict__ hh_rs, const int* __restrict__ hh_cur,
    const uint32_t* __restrict__ hh_ent,
    const __half* __restrict__ pre_t,
    const __half* __restrict__ hprev,
    __half* __restrict__ hnext) {
  int r = (blockIdx.x * 256 + threadIdx.x) >> 6;
  int lane = threadIdx.x & 63;
  int q = lane >> 4, p = lane & 15;
  int s0  = __builtin_amdgcn_readfirstlane(hh_rs[r]);       // multiple of 32
  int cnt = __builtin_amdgcn_readfirstlane(hh_cur[r]) - s0;
  int nb = (cnt + 31) >> 5;                                 // 32-entry super-blocks
  const int4* ep = (const int4*)(hh_ent + s0);
  const uint32_t* hp = (const uint32_t*)hprev;              // 16 uints per h-row
  uint32_t pu = ((const uint32_t*)pre_t)[(r << 4) + p];
  float2 pre2 = __half22float2(*(__half2*)&pu);

  float2 a0 = {0.f, 0.f}, a1 = {0.f, 0.f}, a2 = {0.f, 0.f}, a3 = {0.f, 0.f};
  int4 fa = ep[q], fb = ep[q + 4];
  for (int i = 0; i < nb; i++) {
    int4 ea = fa, eb = fb;
    fa = ep[8 * (i + 1) + q];                               // prefetch (slack-safe)
    fb = ep[8 * (i + 1) + q + 4];
    uint32_t u0 = (uint32_t)ea.x, u1 = (uint32_t)ea.y, u2 = (uint32_t)ea.z, u3 = (uint32_t)ea.w;
    uint32_t u4 = (uint32_t)eb.x, u5 = (uint32_t)eb.y, u6 = (uint32_t)eb.z, u7 = (uint32_t)eb.w;
    uint32_t g0 = hp[((u0 & 0xffff) << 4) + p];
    uint32_t g1 = hp[((u1 & 0xffff) << 4) + p];
    uint32_t g2 = hp[((u2 & 0xffff) << 4) + p];
    uint32_t g3 = hp[((u3 & 0xffff) << 4) + p];
    uint32_t g4 = hp[((u4 & 0xffff) << 4) + p];
    uint32_t g5 = hp[((u5 & 0xffff) << 4) + p];
    uint32_t g6 = hp[((u6 & 0xffff) << 4) + p];
    uint32_t g7 = hp[((u7 & 0xffff) << 4) + p];
    float v0 = entval(u0), v1 = entval(u1), v2 = entval(u2), v3 = entval(u3);
    float v4 = entval(u4), v5 = entval(u5), v6 = entval(u6), v7 = entval(u7);
    float2 x0 = __half22float2(*(__half2*)&g0), x1 = __half22float2(*(__half2*)&g1);
    float2 x2v = __half22float2(*(__half2*)&g2), x3 = __half22float2(*(__half2*)&g3);
    float2 x4 = __half22float2(*(__half2*)&g4), x5 = __half22float2(*(__half2*)&g5);
    float2 x6 = __half22float2(*(__half2*)&g6), x7 = __half22float2(*(__half2*)&g7);
    a0.x += v0 * x0.x;  a0.y += v0 * x0.y;   a0.x += v4 * x4.x;  a0.y += v4 * x4.y;
    a1.x += v1 * x1.x;  a1.y += v1 * x1.y;   a1.x += v5 * x5.x;  a1.y += v5 * x5.y;
    a2.x += v2 * x2v.x; a2.y += v2 * x2v.y;  a2.x += v6 * x6.x;  a2.y += v6 * x6.y;
    a3.x += v3 * x3.x;  a3.y += v3 * x3.y;   a3.x += v7 * x7.x;  a3.y += v7 * x7.y;
  }
  float ax = (a0.x + a1.x) + (a2.x + a3.x);
  float ay = (a0.y + a1.y) + (a2.y + a3.y);
  ax += __shfl_xor(ax, 16, 64);  ay += __shfl_xor(ay, 16, 64);
  ax += __shfl_xor(ax, 32, 64);  ay += __shfl_xor(ay, 32, 64);
  float hv0 = 1.0f / (1.0f + __expf(-(pre2.x + ax)));
  float hv1 = 1.0f / (1.0f + __expf(-(pre2.y + ay)));
  if (q == 0) ((__half2*)hnext)[(r << 4) + p] = __floats2half2_rn(hv0, hv1);
}

// ---------------- Output spmm, XCD-partitioned by time, fp16 h ----------------
// Quarter-split (R12 form).
__global__ void __launch_bounds__(256, 8) out_kernel(
    const int* __restrict__ ho_rs, const int* __restrict__ ho_cur,
    const uint32_t* __restrict__ ho_ent,
    const float* __restrict__ ho_bias, const __half* __restrict__ hAll,
    float* __restrict__ out_tmp) {
  int xcd = blockIdx.x & 7;
  int w   = (blockIdx.x >> 3) * 4 + (threadIdx.x >> 6);
  int lane = threadIdx.x & 63;
  int q = lane >> 4, p = lane & 15;
  int t0 = xcd * 4;
  constexpr int HU = Hh * 16;                               // uints per t-slice
  const uint32_t* hb = (const uint32_t*)hAll + (size_t)(t0 + 1) * HU;

  for (int o = w; o < Oo; o += 1024) {
    int s0  = __builtin_amdgcn_readfirstlane(ho_rs[o]);     // multiple of 32
    int cnt = __builtin_amdgcn_readfirstlane(ho_cur[o]) - s0;
    int nb = (cnt + 15) >> 4;                               // 16-entry blocks
    const int4* ep = (const int4*)(ho_ent + s0);
    float2 A0 = {0.f, 0.f}, A1 = {0.f, 0.f}, A2 = {0.f, 0.f}, A3 = {0.f, 0.f};
    int4 f = ep[q];
    for (int i = 0; i < nb; i++) {
      int4 e = f;
      f = ep[4 * (i + 1) + q];                              // prefetch (pad/slack-safe)
      uint32_t u0 = (uint32_t)e.x, u1 = (uint32_t)e.y, u2 = (uint32_t)e.z, u3 = (uint32_t)e.w;
      int b0 = (int)((u0 & 0xffff) << 4) + p;
      int b1 = (int)((u1 & 0xffff) << 4) + p;
      int b2 = (int)((u2 & 0xffff) << 4) + p;
      int b3 = (int)((u3 & 0xffff) << 4) + p;
      float v0 = entval(u0), v1 = entval(u1), v2 = entval(u2), v3 = entval(u3);
      {
        uint32_t g0 = hb[b0], g1 = hb[b0 + HU], g2 = hb[b0 + 2 * HU], g3 = hb[b0 + 3 * HU];
        float2 x0 = __half22float2(*(__half2*)&g0), x1 = __half22float2(*(__half2*)&g1);
        float2 x2v = __half22float2(*(__half2*)&g2), x3 = __half22float2(*(__half2*)&g3);
        A0.x += v0 * x0.x;  A0.y += v0 * x0.y;
        A1.x += v0 * x1.x;  A1.y += v0 * x1.y;
        A2.x += v0 * x2v.x; A2.y += v0 * x2v.y;
        A3.x += v0 * x3.x;  A3.y += v0 * x3.y;
      }
      {
        uint32_t g0 = hb[b1], g1 = hb[b1 + HU], g2 = hb[b1 + 2 * HU], g3 = hb[b1 + 3 * HU];
        float2 x0 = __half22float2(*(__half2*)&g0), x1 = __half22float2(*(__half2*)&g1);
        float2 x2v = __half22float2(*(__half2*)&g2), x3 = __half22float2(*(__half2*)&g3);
        A0.x += v1 * x0.x;  A0.y += v1 * x0.y;
        A1.x += v1 * x1.x;  A1.y += v1 * x1.y;
        A2.x += v1 * x2v.x; A2.y += v1 * x2v.y;
        A3.x += v1 * x3.x;  A3.y += v1 * x3.y;
      }
      {
        uint32_t g0 = hb[b2], g1 = hb[b2 + HU], g2 = hb[b2 + 2 * HU], g3 = hb[b2 + 3 * HU];
        float2 x0 = __half22float2(*(__half2*)&g0), x1 = __half22float2(*(__half2*)&g1);
        float2 x2v = __half22float2(*(__half2*)&g2), x3 = __half22float2(*(__half2*)&g3);
        A0.x += v2 * x0.x;  A0.y += v2 * x0.y;
        A1.x += v2 * x1.x;  A1.y += v2 * x1.y;
        A2.x += v2 * x2v.x; A2.y += v2 * x2v.y;
        A3.x += v2 * x3.x;  A3.y += v2 * x3.y;
      }
      {
        uint32_t g0 = hb[b3], g1 = hb[b3 + HU], g2 = hb[b3 + 2 * HU], g3 = hb[b3 + 3 * HU];
        float2 x0 = __half22float2(*(__half2*)&g0), x1 = __half22float2(*(__half2*)&g1);
        float2 x2v = __half22float2(*(__half2*)&g2), x3 = __half22float2(*(__half2*)&g3);
        A0.x += v3 * x0.x;  A0.y += v3 * x0.y;
        A1.x += v3 * x1.x;  A1.y += v3 * x1.y;
        A2.x += v3 * x2v.x; A2.y += v3 * x2v.y;
        A3.x += v3 * x3.x;  A3.y += v3 * x3.y;
      }
    }
    A0.x += __shfl_xor(A0.x, 16, 64);  A0.y += __shfl_xor(A0.y, 16, 64);
    A1.x += __shfl_xor(A1.x, 16, 64);  A1.y += __shfl_xor(A1.y, 16, 64);
    A2.x += __shfl_xor(A2.x, 16, 64);  A2.y += __shfl_xor(A2.y, 16, 64);
    A3.x += __shfl_xor(A3.x, 16, 64);  A3.y += __shfl_xor(A3.y, 16, 64);
    A0.x += __shfl_xor(A0.x, 32, 64);  A0.y += __shfl_xor(A0.y, 32, 64);
    A1.x += __shfl_xor(A1.x, 32, 64);  A1.y += __shfl_xor(A1.y, 32, 64);
    A2.x += __shfl_xor(A2.x, 32, 64);  A2.y += __shfl_xor(A2.y, 32, 64);
    A3.x += __shfl_xor(A3.x, 32, 64);  A3.y += __shfl_xor(A3.y, 32, 64);
    if (q == 0) {
      float bias = ho_bias[o];
      float2* ot = (float2*)out_tmp;
      ot[(((size_t)(t0 + 0) * Oo + o) * Bb >> 1) + p] = {A0.x + bias, A0.y + bias};
      ot[(((size_t)(t0 + 1) * Oo + o) * Bb >> 1) + p] = {A1.x + bias, A1.y + bias};
      ot[(((size_t)(t0 + 2) * Oo + o) * Bb >> 1) + p] = {A2.x + bias, A2.y + bias};
      ot[(((size_t)(t0 + 3) * Oo + o) * Bb >> 1) + p] = {A3.x + bias, A3.y + bias};
    }
  }
}

// ---------------- out transpose: (T,O,B) -> (B,T,O), fp32 ----------------
__global__ void transpose_out_kernel(const float* __restrict__ out_tmp, float* __restrict__ dout) {
  int blk = blockIdx.x;
  int t  = blk >> 5;
  int o0 = (blk & 31) << 6;
  __shared__ float lds[64][33];
  int tid = threadIdx.x;
  for (int idx = tid; idx < 64 * 32; idx += 256) {
    int ol = idx >> 5, bb = idx & 31;
    lds[ol][bb] = out_tmp[(size_t)t * Oo * Bb + (size_t)(o0 + ol) * Bb + bb];
  }
  __syncthreads();
  for (int idx = tid; idx < 32 * 64; idx += 256) {
    int bb = idx >> 6, ol = idx & 63;
    dout[(size_t)bb * Tt * Oo + (size_t)t * Oo + o0 + ol] = lds[ol][bb];
  }
}

extern "C" void kernel_launch(void* const* d_in, const int* in_sizes, int n_in,
                              void* d_out, int out_size, void* d_ws, size_t ws_size,
                              hipStream_t stream) {
  const float* x       = (const float*)d_in[0];
  const int*   hh_rows = (const int*)d_in[1];
  const int*   hh_cols = (const int*)d_in[2];
  const float* hh_vals = (const float*)d_in[3];
  const float* hh_bias = (const float*)d_in[4];
  const int*   ih_rows = (const int*)d_in[5];
  const int*   ih_cols = (const int*)d_in[6];
  const float* ih_vals = (const float*)d_in[7];
  const int*   ho_rows = (const int*)d_in[8];
  const int*   ho_cols = (const int*)d_in[9];
  const float* ho_vals = (const float*)d_in[10];
  const float* ho_bias = (const float*)d_in[11];
  float* out = (float*)d_out;

  const int nnz_hh = in_sizes[1];
  const int nnz_ih = in_sizes[5];
  const int nnz_ho = in_sizes[8];

  const int ntile_ih = (nnz_ih + TILE - 1) / TILE;
  const int ntile_hh = (nnz_hh + TILE - 1) / TILE;
  const int ntile_ho = (nnz_ho + TILE - 1) / TILE;

  // Workspace carve-up (~72 MB)
  char* w = (char*)d_ws;
  size_t off = 0;
  auto alloc = [&](size_t bytes) -> void* {
    void* p = w + off;
    off += (bytes + 255) & ~(size_t)255;
    return p;
  };
  __half* x2h    = (__half*)alloc(2 * (size_t)Ii * TB);                 // 16 MB
  __half* hAll   = (__half*)alloc(2 * (size_t)(Tt + 1) * Hh * Bb);      // 16.5 MB
  __half* preAll = (__half*)alloc(2 * (size_t)Tt * Hh * Bb);            // 16 MB
  float* out_tmp = (float*)alloc(4 * (size_t)Tt * Oo * Bb);             // 8 MB
  int*  ih_rs  = (int*)alloc(4 * (size_t)(Hh + 1));
  int*  hh_rs  = (int*)alloc(4 * (size_t)(Hh + 1));
  int*  ho_rs  = (int*)alloc(4 * (size_t)(Oo + 1));
  int*  cur_all = (int*)alloc(4 * (size_t)(Hh + Hh + Oo));   // fully written by rowcount
  int*  ih_cur = cur_all;
  int*  hh_cur = cur_all + Hh;
  int*  ho_cur = cur_all + 2 * Hh;
  uint32_t* ih_ent = (uint32_t*)alloc(4 * ((size_t)nnz_ih + 32 * Hh + 128));  // pad32 + slack
  uint32_t* hh_ent = (uint32_t*)alloc(4 * ((size_t)nnz_hh + 32 * Hh + 128));
  uint32_t* ho_ent = (uint32_t*)alloc(4 * ((size_t)nnz_ho + 32 * Oo + 128));
  // counting-sort bookkeeping (fully rewritten each run -> no memset needed)
  int* tb_ih  = (int*)alloc(4 * (size_t)(ntile_ih * NFB_H));
  int* tb_hh  = (int*)alloc(4 * (size_t)(ntile_hh * NFB_H));
  int* tb_ho  = (int*)alloc(4 * (size_t)(ntile_ho * NFB_O));
  int* fbb_ih = (int*)alloc(4 * (size_t)(NFB_H + 1));
  int* fbb_hh = (int*)alloc(4 * (size_t)(NFB_H + 1));
  int* fbb_ho = (int*)alloc(4 * (size_t)(NFB_O + 1));
  int* totals = (int*)alloc(4 * (size_t)(2 * NFB_H + NFB_O));

  // u64 bucket streams overlay preAll (14.7 MB <= 16 MB): consumed by
  // rowcount/csort BEFORE preih writes preAll.
  uint64_t* s_ih = (uint64_t*)preAll;
  uint64_t* s_hh = s_ih + (size_t)nnz_ih;
  uint64_t* s_ho = s_hh + (size_t)nnz_hh;

  // Init (1 memset; cur/tb/entry arrays are fully written by the pipeline)
  hipMemsetAsync(hAll, 0, 2 * (size_t)Hh * Bb, stream);   // h_{-1} = 0 (fp16 zeros)

  // x -> (I,T,B) fp16
  transpose_x_kernel<<<(Tt / 2) * (Ii / 64), 256, 0, stream>>>(x, (__half2*)x2h);

  // CSR build: dense-write counting sort, atomic-free row histogram
  count_kernel<<<ntile_ih + ntile_hh + ntile_ho, 256, 0, stream>>>(
      ih_rows, nnz_ih, tb_ih, ntile_ih,
      hh_rows, nnz_hh, tb_hh, ntile_hh,
      ho_rows, nnz_ho, tb_ho);
  scan_col_kernel<<<2 * NFB_H + NFB_O, 256, 0, stream>>>(
      tb_ih, ntile_ih, tb_hh, ntile_hh, tb_ho, ntile_ho, totals);
  scan_base_kernel<<<3, 256, 0, stream>>>(totals, fbb_ih, fbb_hh, fbb_ho);
  place_kernel<<<ntile_ih + ntile_hh + ntile_ho, 256, 0, stream>>>(
      ih_rows, ih_cols, ih_vals, nnz_ih, tb_ih, ntile_ih, fbb_ih, s_ih,
      hh_rows, hh_cols, hh_vals, nnz_hh, tb_hh, ntile_hh, fbb_hh, s_hh,
      ho_rows, ho_cols, ho_vals, nnz_ho, tb_ho, fbb_ho, s_ho);
  rowcount_kernel<<<2 * NFB_H + NFB_O, 256, 0, stream>>>(
      s_ih, fbb_ih, ih_cur, s_hh, fbb_hh, hh_cur, s_ho, fbb_ho, ho_cur);
  scan_csr_kernel<<<3, 1024, 0, stream>>>(
      ih_cur, Hh, ih_rs, hh_cur, Hh, hh_rs, ho_cur, Oo, ho_rs);
  csort_kernel<<<2 * NFB_H + NFB_O, 256, 0, stream>>>(
      s_ih, fbb_ih, ih_rs, ih_ent,
      s_hh, fbb_hh, hh_rs, hh_ent,
      s_ho, fbb_ho, ho_rs, ho_ent);

  // pre[t][r][b] fp16, XCD-pinned time chunks (half-wave paired gathers)
  preih_kernel<<<8 * Hh / 4, 256, 0, stream>>>(
      ih_rs, ih_cur, ih_ent, hh_bias, x2h, (__half2*)preAll);

  // Recurrence: one dispatch per step
  for (int t = 0; t < Tt; t++) {
    step_kernel<<<Hh / 4, 256, 0, stream>>>(
        hh_rs, hh_cur, hh_ent,
        preAll + (size_t)t * Hh * Bb,
        hAll + (size_t)t * Hh * Bb,
        hAll + (size_t)(t + 1) * Hh * Bb);
  }

  // Output spmm (XCD t-partitioned) + final transpose
  out_kernel<<<2048, 256, 0, stream>>>(
      ho_rs, ho_cur, ho_ent, ho_bias, hAll, out_tmp);
  transpose_out_kernel<<<Tt * (Oo / 64), 256, 0, stream>>>(out_tmp, out);

  (void)n_in; (void)out_size; (void)ws_size;
}

// Round 14
// 529.370 us; speedup vs baseline: 1.0354x; 1.0354x over previous
//
#include <hip/hip_runtime.h>
#include <hip/hip_fp16.h>

// Problem constants (fixed by the reference)
constexpr int Bb = 32;     // batch
constexpr int Tt = 32;     // time steps
constexpr int Ii = 8192;   // input dim
constexpr int Hh = 8192;   // hidden dim
constexpr int Oo = 2048;   // output dim
constexpr int TB = Tt * Bb;  // halves per x2 column = 1024
constexpr int TCH = 4;       // timesteps per XCD chunk
constexpr int TILE = 2048;   // COO entries per tile
constexpr int FBR = 32;      // rows per fine bucket
constexpr int NFB_H = Hh / FBR;  // 256
constexpr int NFB_O = Oo / FBR;  // 64

// Entry packing: lo16 = col (u16), hi16 = fp16 value bits. 4 B/entry.
// Rows padded to multiples of 32 entries (128 B) -> 2x int4 per quarter-wave.
//
// Journal of failed experiments (do not retry):
//  - R1: XCD row-partitioned single-pass scatter: 8x COO re-scan -> +74 MB
//    FETCH, write amp stayed (94->64 MB). Regressed 117->164 us.
//  - R2: all-32-step cooperative kernel w/ grid.sync(): ~280 us PER SYNC at
//    2048 blocks. 24x regression. Dispatch boundaries are the cheap sync.
//  - R3/R4: __builtin_nontemporal_load build -> container failed twice. Avoid.
//  - R6: partition-local bscatter: WRITE still 53.6 MB = 7.3x payload. gfx950
//    stores do NOT write-allocate in L2; random 4B stores have a ~7-8x HBM
//    write-amp floor. Dense writes only.
//  - R7: metadata scans need block-level parallelism.
//  - R8: cross-XCD contended global atomics pay HBM (L2 line ping-pong);
//    derive histograms from bucketed data.
//  - R10: preih single-pass (all 32 t per wave) = L2 thrash (402 MB, 2x
//    worse). Keep gather working sets L2-resident even at the cost of
//    redundant instruction work.
//  - R12: step 2x unroll + out quarter-split = -4.8 us only. The 32 step
//    dispatches are LAUNCH/LATENCY-bound (~6 us/step overhead), not
//    issue-bound. The recurrence is at its structural floor.
//  - R13: preih half-wave paired uint2 gathers: VALU down (77->65%) but dur
//    61.6->79.6 us. Halving the number of in-flight gathers exposes latency;
//    in gather-heavy loops, many small independent loads > fewer wide loads.

__device__ __forceinline__ float entval(uint32_t u) {
  return __half2float(__ushort_as_half((unsigned short)(u >> 16)));
}

// ---------------- x transpose: (B,T,I) fp32 -> (I,T,B) fp16 ----------------
__global__ void transpose_x_kernel(const float* __restrict__ x, __half2* __restrict__ x2) {
  int blk = blockIdx.x;          // (Tt/2) * (Ii/64) = 2048 blocks
  int tp = blk >> 7;
  int ib = blk & 127;
  int t0 = tp * 2;
  int i0 = ib * 64;
  __shared__ float lds[64][65];
  int tid = threadIdx.x;
  for (int idx = tid; idx < 64 * 64; idx += 256) {
    int row = idx >> 6, il = idx & 63;     // coalesced reads along i
    int tt = row >> 5, bb = row & 31;
    lds[il][row] = x[(size_t)bb * Tt * Ii + (size_t)(t0 + tt) * Ii + i0 + il];
  }
  __syncthreads();
  for (int idx = tid; idx < 64 * 32; idx += 256) {
    int il = idx >> 5;
    int q = idx & 31;
    int tt = q >> 4, p = q & 15;           // b-pair p -> batches 2p, 2p+1
    float lo = lds[il][tt * 32 + 2 * p];
    float hi = lds[il][tt * 32 + 2 * p + 1];
    x2[(size_t)(i0 + il) * (TB / 2) + (size_t)(t0 + tt) * 16 + p] = __floats2half2_rn(lo, hi);
  }
}

// ---------------- CSR build: dense-write counting sort ----------------
// Phase 1: per-(tile, 32-row fbucket) counts ONLY (LDS atomics, dense write).
__global__ void __launch_bounds__(256) count_kernel(
    const int* __restrict__ r1, int n1, int* __restrict__ tb1, int nt1,
    const int* __restrict__ r2, int n2, int* __restrict__ tb2, int nt2,
    const int* __restrict__ r3, int n3, int* __restrict__ tb3) {
  __shared__ int cnt[NFB_H];
  int tile = blockIdx.x;
  const int* rows; int n; int* tb; int tl; int nfb;
  if (tile < nt1)            { rows = r1; n = n1; tb = tb1; tl = tile;             nfb = NFB_H; }
  else if (tile < nt1 + nt2) { rows = r2; n = n2; tb = tb2; tl = tile - nt1;       nfb = NFB_H; }
  else                       { rows = r3; n = n3; tb = tb3; tl = tile - nt1 - nt2; nfb = NFB_O; }
  for (int i = threadIdx.x; i < nfb; i += 256) cnt[i] = 0;
  __syncthreads();
  int base = tl * TILE;
  for (int k = threadIdx.x; k < TILE; k += 256) {
    int j = base + k;
    if (j < n) atomicAdd(&cnt[rows[j] >> 5], 1);     // fine-bucket count (LDS)
  }
  __syncthreads();
  for (int i = threadIdx.x; i < nfb; i += 256) tb[tl * nfb + i] = cnt[i];
}

// Phase 2b: per-column (fbucket) exclusive scan over tiles, block-parallel.
__global__ void __launch_bounds__(256) scan_col_kernel(
    int* __restrict__ tb1, int nt1, int* __restrict__ tb2, int nt2,
    int* __restrict__ tb3, int nt3, int* __restrict__ totals) {
  __shared__ int sums[256];
  int col = blockIdx.x;
  int* tb; int nt; int fb; int nfb;
  if (col < NFB_H)          { tb = tb1; nt = nt1; fb = col;             nfb = NFB_H; }
  else if (col < 2 * NFB_H) { tb = tb2; nt = nt2; fb = col - NFB_H;     nfb = NFB_H; }
  else                      { tb = tb3; nt = nt3; fb = col - 2 * NFB_H; nfb = NFB_O; }
  int tid = threadIdx.x;
  int nper = (nt + 255) >> 8;            // <=2 at these sizes
  int vals[8];                            // slack
  int t0 = tid * nper;
  int a = 0;
  for (int i = 0; i < nper; i++) {
    int t = t0 + i;
    vals[i] = (t < nt) ? tb[t * nfb + fb] : 0;
    a += vals[i];
  }
  sums[tid] = a;
  __syncthreads();
  for (int off = 1; off < 256; off <<= 1) {
    int o = (tid >= off) ? sums[tid - off] : 0;
    __syncthreads();
    sums[tid] += o;
    __syncthreads();
  }
  int run = sums[tid] - a;
  for (int i = 0; i < nper; i++) {
    int t = t0 + i;
    if (t < nt) { tb[t * nfb + fb] = run; run += vals[i]; }
  }
  if (tid == 255) totals[col] = sums[255];
}

// Phase 2c: exclusive scan of column totals -> bucket bases fbb[nfb+1].
__global__ void __launch_bounds__(256) scan_base_kernel(
    const int* __restrict__ totals, int* __restrict__ fbb1,
    int* __restrict__ fbb2, int* __restrict__ fbb3) {
  __shared__ int s[256];
  int m = blockIdx.x;
  const int* t; int* fbb; int nfb;
  if (m == 0)      { t = totals;             fbb = fbb1; nfb = NFB_H; }
  else if (m == 1) { t = totals + NFB_H;     fbb = fbb2; nfb = NFB_H; }
  else             { t = totals + 2 * NFB_H; fbb = fbb3; nfb = NFB_O; }
  int tid = threadIdx.x;
  int v = (tid < nfb) ? t[tid] : 0;
  s[tid] = v;
  __syncthreads();
  for (int off = 1; off < 256; off <<= 1) {
    int o = (tid >= off) ? s[tid - off] : 0;
    __syncthreads();
    s[tid] += o;
    __syncthreads();
  }
  if (tid < nfb) fbb[tid] = s[tid] - v;
  if (tid == 255) fbb[nfb] = s[255];
}

// Phase 3: LDS-staged binning -> DENSE u64 stream writes (entry<<32 | row).
__global__ void __launch_bounds__(256) place_kernel(
    const int* __restrict__ r1, const int* __restrict__ c1, const float* __restrict__ v1,
    int n1, const int* __restrict__ tb1, int nt1, const int* __restrict__ fbb1, uint64_t* __restrict__ s1,
    const int* __restrict__ r2, const int* __restrict__ c2, const float* __restrict__ v2,
    int n2, const int* __restrict__ tb2, int nt2, const int* __restrict__ fbb2, uint64_t* __restrict__ s2,
    const int* __restrict__ r3, const int* __restrict__ c3, const float* __restrict__ v3,
    int n3, const int* __restrict__ tb3, const int* __restrict__ fbb3, uint64_t* __restrict__ s3) {
  __shared__ int cnt[NFB_H];
  __shared__ int incl[NFB_H];
  __shared__ uint64_t stg[TILE];
  __shared__ int gad[TILE];
  int tile = blockIdx.x;
  const int* rows; const int* cols; const float* vals; int n;
  const int* tb; const int* fbb; uint64_t* st; int tl; int nfb;
  if (tile < nt1)            { rows = r1; cols = c1; vals = v1; n = n1; tb = tb1; fbb = fbb1; st = s1; tl = tile;             nfb = NFB_H; }
  else if (tile < nt1 + nt2) { rows = r2; cols = c2; vals = v2; n = n2; tb = tb2; fbb = fbb2; st = s2; tl = tile - nt1;       nfb = NFB_H; }
  else                       { rows = r3; cols = c3; vals = v3; n = n3; tb = tb3; fbb = fbb3; st = s3; tl = tile - nt1 - nt2; nfb = NFB_O; }
  int tid = threadIdx.x;
  for (int i = tid; i < NFB_H; i += 256) cnt[i] = 0;   // zero full 256 (scan below is fixed-width)
  __syncthreads();
  constexpr int E = TILE / 256;                        // 8 entries/thread
  uint32_t entv[E]; int rowv[E]; int rnkv[E];
  int base = tl * TILE;
  for (int k = 0; k < E; k++) {
    int j = base + k * 256 + tid;
    if (j < n) {
      int rr = rows[j];
      rowv[k] = rr;
      entv[k] = ((uint32_t)__half_as_ushort(__float2half_rn(vals[j])) << 16) | (uint32_t)cols[j];
      rnkv[k] = atomicAdd(&cnt[rr >> 5], 1);
    } else {
      rowv[k] = -1;
    }
  }
  __syncthreads();
  // inclusive scan of cnt[0..255] -> incl (Hillis-Steele)
  int v0 = cnt[tid];
  incl[tid] = v0;
  __syncthreads();
  for (int off = 1; off < 256; off <<= 1) {
    int o = (tid >= off) ? incl[tid - off] : 0;
    __syncthreads();
    incl[tid] += o;
    __syncthreads();
  }
  int total = incl[255];
  for (int k = 0; k < E; k++) {
    if (rowv[k] >= 0) {
      int fb = rowv[k] >> 5;
      int slot = (incl[fb] - cnt[fb]) + rnkv[k];       // exclusive offset + rank
      stg[slot] = ((uint64_t)entv[k] << 32) | (uint32_t)rowv[k];
      gad[slot] = fbb[fb] + tb[tl * nfb + fb] + rnkv[k];
    }
  }
  __syncthreads();
  for (int i = tid; i < total; i += 256) st[gad[i]] = stg[i];
}

// Phase 3b: per-row histogram from the bucketed stream (atomic-free global).
__global__ void __launch_bounds__(256) rowcount_kernel(
    const uint64_t* __restrict__ s1, const int* __restrict__ fbb1, int* __restrict__ cu1,
    const uint64_t* __restrict__ s2, const int* __restrict__ fbb2, int* __restrict__ cu2,
    const uint64_t* __restrict__ s3, const int* __restrict__ fbb3, int* __restrict__ cu3) {
  __shared__ int rc[FBR];
  int bx = blockIdx.x;
  const uint64_t* st; const int* fbb; int* cu; int b;
  if (bx < NFB_H)          { st = s1; fbb = fbb1; cu = cu1; b = bx; }
  else if (bx < 2 * NFB_H) { st = s2; fbb = fbb2; cu = cu2; b = bx - NFB_H; }
  else                     { st = s3; fbb = fbb3; cu = cu3; b = bx - 2 * NFB_H; }
  int tid = threadIdx.x;
  if (tid < FBR) rc[tid] = 0;
  __syncthreads();
  int lo = fbb[b], hi = fbb[b + 1];
  for (int j = lo + tid; j < hi; j += 256)
    atomicAdd(&rc[(int)(uint32_t)st[j] & (FBR - 1)], 1);
  __syncthreads();
  if (tid < FBR) cu[(b << 5) + tid] = rc[tid];
}

// Phase 2a (after rowcount): CSR exclusive scan; rows padded to 32 entries.
// rs[r]=start (32-padded), cur[r]=rs+cnt (end pointer).
__global__ void scan_csr_kernel(int* __restrict__ c1, int n1, int* __restrict__ r1,
                                int* __restrict__ c2, int n2, int* __restrict__ r2,
                                int* __restrict__ c3, int n3, int* __restrict__ r3) {
  __shared__ int sums[1024];
  int bx = blockIdx.x;
  int tid = threadIdx.x;
  int* cnt_cursor; int n; int* row_start;
  if (bx == 0)      { cnt_cursor = c1; n = n1; row_start = r1; }
  else if (bx == 1) { cnt_cursor = c2; n = n2; row_start = r2; }
  else              { cnt_cursor = c3; n = n3; row_start = r3; }
  int chunk = (n + 1023) >> 10;
  int base = tid * chunk;
  int s = 0;
  for (int i = 0; i < chunk; i++) {
    int idx = base + i;
    if (idx < n) s += (cnt_cursor[idx] + 31) & ~31;
  }
  sums[tid] = s;
  __syncthreads();
  for (int off = 1; off < 1024; off <<= 1) {
    int other = (tid >= off) ? sums[tid - off] : 0;
    __syncthreads();
    sums[tid] += other;
    __syncthreads();
  }
  int run = sums[tid] - s;
  for (int i = 0; i < chunk; i++) {
    int idx = base + i;
    if (idx < n) {
      int v = cnt_cursor[idx];
      row_start[idx] = run;
      cnt_cursor[idx] = run + v;     // end pointer (unpadded)
      run += (v + 31) & ~31;
    }
  }
  if (tid == 1023) row_start[n] = sums[1023];
}

// Phase 4: one block per 32-row fbucket: reorder into exact padded-CSR layout
// in LDS (pads zeroed), flush with fully-coalesced stores.
__global__ void __launch_bounds__(256) csort_kernel(
    const uint64_t* __restrict__ s1, const int* __restrict__ fbb1, const int* __restrict__ rs1, uint32_t* __restrict__ e1,
    const uint64_t* __restrict__ s2, const int* __restrict__ fbb2, const int* __restrict__ rs2, uint32_t* __restrict__ e2,
    const uint64_t* __restrict__ s3, const int* __restrict__ fbb3, const int* __restrict__ rs3, uint32_t* __restrict__ e3) {
  __shared__ uint32_t ob[8192];
  __shared__ int rcnt[FBR];
  __shared__ int rsl[FBR + 1];
  int bx = blockIdx.x;
  const uint64_t* st; const int* fbb; const int* rs; uint32_t* e; int b;
  if (bx < NFB_H)            { st = s1; fbb = fbb1; rs = rs1; e = e1; b = bx; }
  else if (bx < 2 * NFB_H)   { st = s2; fbb = fbb2; rs = rs2; e = e2; b = bx - NFB_H; }
  else                       { st = s3; fbb = fbb3; rs = rs3; e = e3; b = bx - 2 * NFB_H; }
  int tid = threadIdx.x;
  if (tid <= FBR) rsl[tid] = rs[(b << 5) + tid];
  if (tid < FBR) rcnt[tid] = 0;
  __syncthreads();
  int reg0 = rsl[0];
  int rlen = rsl[FBR] - reg0;
  int lo = fbb[b], hi = fbb[b + 1];
  if (rlen <= 8192) {
    for (int i = tid; i < rlen; i += 256) ob[i] = 0;
    __syncthreads();
    for (int j = lo + tid; j < hi; j += 256) {
      uint64_t v = st[j];
      int rl = (int)(uint32_t)v & (FBR - 1);
      int rk = atomicAdd(&rcnt[rl], 1);
      ob[(rsl[rl] - reg0) + rk] = (uint32_t)(v >> 32);
    }
    __syncthreads();
    for (int i = tid; i < rlen; i += 256) e[reg0 + i] = ob[i];
  } else {
    // paranoia fallback (never expected at these densities)
    for (int i = tid; i < rlen; i += 256) e[reg0 + i] = 0;
    __syncthreads();
    for (int j = lo + tid; j < hi; j += 256) {
      uint64_t v = st[j];
      int rl = (int)(uint32_t)v & (FBR - 1);
      int rk = atomicAdd(&rcnt[rl], 1);
      e[rsl[rl] + rk] = (uint32_t)(v >> 32);
    }
  }
}

// ---------------- preIH, XCD-pinned time chunks, fp16 data ----------------
// (R9/R12 form, restored after R13's paired-gather regression.) xcd=blockIdx&7
// owns t-chunk [4*xcd, 4*xcd+4): 2 MB fp16 x2 slice stays L2-resident.
// Lane covers (tt = lane>>4, b-pair = lane&15); 8 independent 4B gathers per
// 8-entry block keep latency hidden.
__global__ void __launch_bounds__(256, 8) preih_kernel(
    const int* __restrict__ ih_rs, const int* __restrict__ ih_cur,
    const uint32_t* __restrict__ ih_ent,
    const float* __restrict__ hh_bias, const __half* __restrict__ x2h,
    __half2* __restrict__ preAll) {
  int xcd = blockIdx.x & 7;
  int r = ((blockIdx.x >> 3) << 2) + (threadIdx.x >> 6);
  int lane = threadIdx.x & 63;
  int t0 = xcd * TCH;
  int s0  = __builtin_amdgcn_readfirstlane(ih_rs[r]);       // multiple of 32
  int cnt = __builtin_amdgcn_readfirstlane(ih_cur[r]) - s0;
  int nb = (cnt + 7) >> 3;                                  // 8-entry blocks
  const int4* ep = (const int4*)(ih_ent + s0);
  const uint32_t* xb = (const uint32_t*)(x2h + (size_t)t0 * Bb);  // + c*(TB/2) uints

  float2 a0 = {0.f, 0.f}, a1 = {0.f, 0.f}, a2 = {0.f, 0.f}, a3 = {0.f, 0.f};
  int4 f0 = ep[0], f1 = ep[1];
  for (int i = 0; i < nb; i++) {
    int4 e0 = f0, e1 = f1;
    f0 = ep[2 * i + 2];            // prefetch next block during gathers
    f1 = ep[2 * i + 3];
    uint32_t u0 = (uint32_t)e0.x, u1 = (uint32_t)e0.y, u2 = (uint32_t)e0.z, u3 = (uint32_t)e0.w;
    uint32_t u4 = (uint32_t)e1.x, u5 = (uint32_t)e1.y, u6 = (uint32_t)e1.z, u7 = (uint32_t)e1.w;
    uint32_t g0 = xb[(size_t)(u0 & 0xffff) * (TB / 2) + lane];
    uint32_t g1 = xb[(size_t)(u1 & 0xffff) * (TB / 2) + lane];
    uint32_t g2 = xb[(size_t)(u2 & 0xffff) * (TB / 2) + lane];
    uint32_t g3 = xb[(size_t)(u3 & 0xffff) * (TB / 2) + lane];
    uint32_t g4 = xb[(size_t)(u4 & 0xffff) * (TB / 2) + lane];
    uint32_t g5 = xb[(size_t)(u5 & 0xffff) * (TB / 2) + lane];
    uint32_t g6 = xb[(size_t)(u6 & 0xffff) * (TB / 2) + lane];
    uint32_t g7 = xb[(size_t)(u7 & 0xffff) * (TB / 2) + lane];
    float v0 = entval(u0), v1 = entval(u1), v2 = entval(u2), v3 = entval(u3);
    float v4 = entval(u4), v5 = entval(u5), v6 = entval(u6), v7 = entval(u7);
    float2 x0 = __half22float2(*(__half2*)&g0), x1 = __half22float2(*(__half2*)&g1);
    float2 x2v = __half22float2(*(__half2*)&g2), x3 = __half22float2(*(__half2*)&g3);
    float2 x4 = __half22float2(*(__half2*)&g4), x5 = __half22float2(*(__half2*)&g5);
    float2 x6 = __half22float2(*(__half2*)&g6), x7 = __half22float2(*(__half2*)&g7);
    a0.x += v0 * x0.x;  a0.y += v0 * x0.y;   a0.x += v4 * x4.x;  a0.y += v4 * x4.y;
    a1.x += v1 * x1.x;  a1.y += v1 * x1.y;   a1.x += v5 * x5.x;  a1.y += v5 * x5.y;
    a2.x += v2 * x2v.x; a2.y += v2 * x2v.y;  a2.x += v6 * x6.x;  a2.y += v6 * x6.y;
    a3.x += v3 * x3.x;  a3.y += v3 * x3.y;   a3.x += v7 * x7.x;  a3.y += v7 * x7.y;
  }
  float bias = hh_bias[r];
  float sx = ((a0.x + a1.x) + (a2.x + a3.x)) + bias;
  float sy = ((a0.y + a1.y) + (a2.y + a3.y)) + bias;
  int tt = lane >> 4, p = lane & 15;
  preAll[((size_t)(t0 + tt) * Hh + r) * 16 + p] = __floats2half2_rn(sx, sy);
}

// ---------------- One recurrence step: h_{t+1} = sigmoid(pre_t + HH @ h_t) ----
// Quarter-split + 2x unroll (R12 form; latency/launch-bound, leave alone).
__global__ void __launch_bounds__(256, 8) step_kernel(
    const int* __restrict__ hh_rs, const int* __restrict__ hh_cur,
    const uint32_t* __restrict__ hh_ent,
    const __half* __restrict__ pre_t,
    const __half* __restrict__ hprev,
    __half* __restrict__ hnext) {
  int r = (blockIdx.x * 256 + threadIdx.x) >> 6;
  int lane = threadIdx.x & 63;
  int q = lane >> 4, p = lane & 15;
  int s0  = __builtin_amdgcn_readfirstlane(hh_rs[r]);       // multiple of 32
  int cnt = __builtin_amdgcn_readfirstlane(hh_cur[r]) - s0;
  int nb = (cnt + 31) >> 5;                                 // 32-entry super-blocks
  const int4* ep = (const int4*)(hh_ent + s0);
  const uint32_t* hp = (const uint32_t*)hprev;              // 16 uints per h-row
  uint32_t pu = ((const uint32_t*)pre_t)[(r << 4) + p];
  float2 pre2 = __half22float2(*(__half2*)&pu);

  float2 a0 = {0.f, 0.f}, a1 = {0.f, 0.f}, a2 = {0.f, 0.f}, a3 = {0.f, 0.f};
  int4 fa = ep[q], fb = ep[q + 4];
  for (int i = 0; i < nb; i++) {
    int4 ea = fa, eb = fb;
    fa = ep[8 * (i + 1) + q];                               // prefetch (slack-safe)
    fb = ep[8 * (i + 1) + q + 4];
    uint32_t u0 = (uint32_t)ea.x, u1 = (uint32_t)ea.y, u2 = (uint32_t)ea.z, u3 = (uint32_t)ea.w;
    uint32_t u4 = (uint32_t)eb.x, u5 = (uint32_t)eb.y, u6 = (uint32_t)eb.z, u7 = (uint32_t)eb.w;
    uint32_t g0 = hp[((u0 & 0xffff) << 4) + p];
    uint32_t g1 = hp[((u1 & 0xffff) << 4) + p];
    uint32_t g2 = hp[((u2 & 0xffff) << 4) + p];
    uint32_t g3 = hp[((u3 & 0xffff) << 4) + p];
    uint32_t g4 = hp[((u4 & 0xffff) << 4) + p];
    uint32_t g5 = hp[((u5 & 0xffff) << 4) + p];
    uint32_t g6 = hp[((u6 & 0xffff) << 4) + p];
    uint32_t g7 = hp[((u7 & 0xffff) << 4) + p];
    float v0 = entval(u0), v1 = entval(u1), v2 = entval(u2), v3 = entval(u3);
    float v4 = entval(u4), v5 = entval(u5), v6 = entval(u6), v7 = entval(u7);
    float2 x0 = __half22float2(*(__half2*)&g0), x1 = __half22float2(*(__half2*)&g1);
    float2 x2v = __half22float2(*(__half2*)&g2), x3 = __half22float2(*(__half2*)&g3);
    float2 x4 = __half22float2(*(__half2*)&g4), x5 = __half22float2(*(__half2*)&g5);
    float2 x6 = __half22float2(*(__half2*)&g6), x7 = __half22float2(*(__half2*)&g7);
    a0.x += v0 * x0.x;  a0.y += v0 * x0.y;   a0.x += v4 * x4.x;  a0.y += v4 * x4.y;
    a1.x += v1 * x1.x;  a1.y += v1 * x1.y;   a1.x += v5 * x5.x;  a1.y += v5 * x5.y;
    a2.x += v2 * x2v.x; a2.y += v2 * x2v.y;  a2.x += v6 * x6.x;  a2.y += v6 * x6.y;
    a3.x += v3 * x3.x;  a3.y += v3 * x3.y;   a3.x += v7 * x7.x;  a3.y += v7 * x7.y;
  }
  float ax = (a0.x + a1.x) + (a2.x + a3.x);
  float ay = (a0.y + a1.y) + (a2.y + a3.y);
  ax += __shfl_xor(ax, 16, 64);  ay += __shfl_xor(ay, 16, 64);
  ax += __shfl_xor(ax, 32, 64);  ay += __shfl_xor(ay, 32, 64);
  float hv0 = 1.0f / (1.0f + __expf(-(pre2.x + ax)));
  float hv1 = 1.0f / (1.0f + __expf(-(pre2.y + ay)));
  if (q == 0) ((__half2*)hnext)[(r << 4) + p] = __floats2half2_rn(hv0, hv1);
}

// ---------------- Output spmm, XCD-partitioned by time, fp16 h ----------------
// Quarter-split (R12 form).
__global__ void __launch_bounds__(256, 8) out_kernel(
    const int* __restrict__ ho_rs, const int* __restrict__ ho_cur,
    const uint32_t* __restrict__ ho_ent,
    const float* __restrict__ ho_bias, const __half* __restrict__ hAll,
    float* __restrict__ out_tmp) {
  int xcd = blockIdx.x & 7;
  int w   = (blockIdx.x >> 3) * 4 + (threadIdx.x >> 6);
  int lane = threadIdx.x & 63;
  int q = lane >> 4, p = lane & 15;
  int t0 = xcd * 4;
  constexpr int HU = Hh * 16;                               // uints per t-slice
  const uint32_t* hb = (const uint32_t*)hAll + (size_t)(t0 + 1) * HU;

  for (int o = w; o < Oo; o += 1024) {
    int s0  = __builtin_amdgcn_readfirstlane(ho_rs[o]);     // multiple of 32
    int cnt = __builtin_amdgcn_readfirstlane(ho_cur[o]) - s0;
    int nb = (cnt + 15) >> 4;                               // 16-entry blocks
    const int4* ep = (const int4*)(ho_ent + s0);
    float2 A0 = {0.f, 0.f}, A1 = {0.f, 0.f}, A2 = {0.f, 0.f}, A3 = {0.f, 0.f};
    int4 f = ep[q];
    for (int i = 0; i < nb; i++) {
      int4 e = f;
      f = ep[4 * (i + 1) + q];                              // prefetch (pad/slack-safe)
      uint32_t u0 = (uint32_t)e.x, u1 = (uint32_t)e.y, u2 = (uint32_t)e.z, u3 = (uint32_t)e.w;
      int b0 = (int)((u0 & 0xffff) << 4) + p;
      int b1 = (int)((u1 & 0xffff) << 4) + p;
      int b2 = (int)((u2 & 0xffff) << 4) + p;
      int b3 = (int)((u3 & 0xffff) << 4) + p;
      float v0 = entval(u0), v1 = entval(u1), v2 = entval(u2), v3 = entval(u3);
      {
        uint32_t g0 = hb[b0], g1 = hb[b0 + HU], g2 = hb[b0 + 2 * HU], g3 = hb[b0 + 3 * HU];
        float2 x0 = __half22float2(*(__half2*)&g0), x1 = __half22float2(*(__half2*)&g1);
        float2 x2v = __half22float2(*(__half2*)&g2), x3 = __half22float2(*(__half2*)&g3);
        A0.x += v0 * x0.x;  A0.y += v0 * x0.y;
        A1.x += v0 * x1.x;  A1.y += v0 * x1.y;
        A2.x += v0 * x2v.x; A2.y += v0 * x2v.y;
        A3.x += v0 * x3.x;  A3.y += v0 * x3.y;
      }
      {
        uint32_t g0 = hb[b1], g1 = hb[b1 + HU], g2 = hb[b1 + 2 * HU], g3 = hb[b1 + 3 * HU];
        float2 x0 = __half22float2(*(__half2*)&g0), x1 = __half22float2(*(__half2*)&g1);
        float2 x2v = __half22float2(*(__half2*)&g2), x3 = __half22float2(*(__half2*)&g3);
        A0.x += v1 * x0.x;  A0.y += v1 * x0.y;
        A1.x += v1 * x1.x;  A1.y += v1 * x1.y;
        A2.x += v1 * x2v.x; A2.y += v1 * x2v.y;
        A3.x += v1 * x3.x;  A3.y += v1 * x3.y;
      }
      {
        uint32_t g0 = hb[b2], g1 = hb[b2 + HU], g2 = hb[b2 + 2 * HU], g3 = hb[b2 + 3 * HU];
        float2 x0 = __half22float2(*(__half2*)&g0), x1 = __half22float2(*(__half2*)&g1);
        float2 x2v = __half22float2(*(__half2*)&g2), x3 = __half22float2(*(__half2*)&g3);
        A0.x += v2 * x0.x;  A0.y += v2 * x0.y;
        A1.x += v2 * x1.x;  A1.y += v2 * x1.y;
        A2.x += v2 * x2v.x; A2.y += v2 * x2v.y;
        A3.x += v2 * x3.x;  A3.y += v2 * x3.y;
      }
      {
        uint32_t g0 = hb[b3], g1 = hb[b3 + HU], g2 = hb[b3 + 2 * HU], g3 = hb[b3 + 3 * HU];
        float2 x0 = __half22float2(*(__half2*)&g0), x1 = __half22float2(*(__half2*)&g1);
        float2 x2v = __half22float2(*(__half2*)&g2), x3 = __half22float2(*(__half2*)&g3);
        A0.x += v3 * x0.x;  A0.y += v3 * x0.y;
        A1.x += v3 * x1.x;  A1.y += v3 * x1.y;
        A2.x += v3 * x2v.x; A2.y += v3 * x2v.y;
        A3.x += v3 * x3.x;  A3.y += v3 * x3.y;
      }
    }
    A0.x += __shfl_xor(A0.x, 16, 64);  A0.y += __shfl_xor(A0.y, 16, 64);
    A1.x += __shfl_xor(A1.x, 16, 64);  A1.y += __shfl_xor(A1.y, 16, 64);
    A2.x += __shfl_xor(A2.x, 16, 64);  A2.y += __shfl_xor(A2.y, 16, 64);
    A3.x += __shfl_xor(A3.x, 16, 64);  A3.y += __shfl_xor(A3.y, 16, 64);
    A0.x += __shfl_xor(A0.x, 32, 64);  A0.y += __shfl_xor(A0.y, 32, 64);
    A1.x += __shfl_xor(A1.x, 32, 64);  A1.y += __shfl_xor(A1.y, 32, 64);
    A2.x += __shfl_xor(A2.x, 32, 64);  A2.y += __shfl_xor(A2.y, 32, 64);
    A3.x += __shfl_xor(A3.x, 32, 64);  A3.y += __shfl_xor(A3.y, 32, 64);
    if (q == 0) {
      float bias = ho_bias[o];
      float2* ot = (float2*)out_tmp;
      ot[(((size_t)(t0 + 0) * Oo + o) * Bb >> 1) + p] = {A0.x + bias, A0.y + bias};
      ot[(((size_t)(t0 + 1) * Oo + o) * Bb >> 1) + p] = {A1.x + bias, A1.y + bias};
      ot[(((size_t)(t0 + 2) * Oo + o) * Bb >> 1) + p] = {A2.x + bias, A2.y + bias};
      ot[(((size_t)(t0 + 3) * Oo + o) * Bb >> 1) + p] = {A3.x + bias, A3.y + bias};
    }
  }
}

// ---------------- out transpose: (T,O,B) -> (B,T,O), fp32 ----------------
__global__ void transpose_out_kernel(const float* __restrict__ out_tmp, float* __restrict__ dout) {
  int blk = blockIdx.x;
  int t  = blk >> 5;
  int o0 = (blk & 31) << 6;
  __shared__ float lds[64][33];
  int tid = threadIdx.x;
  for (int idx = tid; idx < 64 * 32; idx += 256) {
    int ol = idx >> 5, bb = idx & 31;
    lds[ol][bb] = out_tmp[(size_t)t * Oo * Bb + (size_t)(o0 + ol) * Bb + bb];
  }
  __syncthreads();
  for (int idx = tid; idx < 32 * 64; idx += 256) {
    int bb = idx >> 6, ol = idx & 63;
    dout[(size_t)bb * Tt * Oo + (size_t)t * Oo + o0 + ol] = lds[ol][bb];
  }
}

extern "C" void kernel_launch(void* const* d_in, const int* in_sizes, int n_in,
                              void* d_out, int out_size, void* d_ws, size_t ws_size,
                              hipStream_t stream) {
  const float* x       = (const float*)d_in[0];
  const int*   hh_rows = (const int*)d_in[1];
  const int*   hh_cols = (const int*)d_in[2];
  const float* hh_vals = (const float*)d_in[3];
  const float* hh_bias = (const float*)d_in[4];
  const int*   ih_rows = (const int*)d_in[5];
  const int*   ih_cols = (const int*)d_in[6];
  const float* ih_vals = (const float*)d_in[7];
  const int*   ho_rows = (const int*)d_in[8];
  const int*   ho_cols = (const int*)d_in[9];
  const float* ho_vals = (const float*)d_in[10];
  const float* ho_bias = (const float*)d_in[11];
  float* out = (float*)d_out;

  const int nnz_hh = in_sizes[1];
  const int nnz_ih = in_sizes[5];
  const int nnz_ho = in_sizes[8];

  const int ntile_ih = (nnz_ih + TILE - 1) / TILE;
  const int ntile_hh = (nnz_hh + TILE - 1) / TILE;
  const int ntile_ho = (nnz_ho + TILE - 1) / TILE;

  // Workspace carve-up (~72 MB)
  char* w = (char*)d_ws;
  size_t off = 0;
  auto alloc = [&](size_t bytes) -> void* {
    void* p = w + off;
    off += (bytes + 255) & ~(size_t)255;
    return p;
  };
  __half* x2h    = (__half*)alloc(2 * (size_t)Ii * TB);                 // 16 MB
  __half* hAll   = (__half*)alloc(2 * (size_t)(Tt + 1) * Hh * Bb);      // 16.5 MB
  __half* preAll = (__half*)alloc(2 * (size_t)Tt * Hh * Bb);            // 16 MB
  float* out_tmp = (float*)alloc(4 * (size_t)Tt * Oo * Bb);             // 8 MB
  int*  ih_rs  = (int*)alloc(4 * (size_t)(Hh + 1));
  int*  hh_rs  = (int*)alloc(4 * (size_t)(Hh + 1));
  int*  ho_rs  = (int*)alloc(4 * (size_t)(Oo + 1));
  int*  cur_all = (int*)alloc(4 * (size_t)(Hh + Hh + Oo));   // fully written by rowcount
  int*  ih_cur = cur_all;
  int*  hh_cur = cur_all + Hh;
  int*  ho_cur = cur_all + 2 * Hh;
  uint32_t* ih_ent = (uint32_t*)alloc(4 * ((size_t)nnz_ih + 32 * Hh + 128));  // pad32 + slack
  uint32_t* hh_ent = (uint32_t*)alloc(4 * ((size_t)nnz_hh + 32 * Hh + 128));
  uint32_t* ho_ent = (uint32_t*)alloc(4 * ((size_t)nnz_ho + 32 * Oo + 128));
  // counting-sort bookkeeping (fully rewritten each run -> no memset needed)
  int* tb_ih  = (int*)alloc(4 * (size_t)(ntile_ih * NFB_H));
  int* tb_hh  = (int*)alloc(4 * (size_t)(ntile_hh * NFB_H));
  int* tb_ho  = (int*)alloc(4 * (size_t)(ntile_ho * NFB_O));
  int* fbb_ih = (int*)alloc(4 * (size_t)(NFB_H + 1));
  int* fbb_hh = (int*)alloc(4 * (size_t)(NFB_H + 1));
  int* fbb_ho = (int*)alloc(4 * (size_t)(NFB_O + 1));
  int* totals = (int*)alloc(4 * (size_t)(2 * NFB_H + NFB_O));

  // u64 bucket streams overlay preAll (14.7 MB <= 16 MB): consumed by
  // rowcount/csort BEFORE preih writes preAll.
  uint64_t* s_ih = (uint64_t*)preAll;
  uint64_t* s_hh = s_ih + (size_t)nnz_ih;
  uint64_t* s_ho = s_hh + (size_t)nnz_hh;

  // Init (1 memset; cur/tb/entry arrays are fully written by the pipeline)
  hipMemsetAsync(hAll, 0, 2 * (size_t)Hh * Bb, stream);   // h_{-1} = 0 (fp16 zeros)

  // x -> (I,T,B) fp16
  transpose_x_kernel<<<(Tt / 2) * (Ii / 64), 256, 0, stream>>>(x, (__half2*)x2h);

  // CSR build: dense-write counting sort, atomic-free row histogram
  count_kernel<<<ntile_ih + ntile_hh + ntile_ho, 256, 0, stream>>>(
      ih_rows, nnz_ih, tb_ih, ntile_ih,
      hh_rows, nnz_hh, tb_hh, ntile_hh,
      ho_rows, nnz_ho, tb_ho);
  scan_col_kernel<<<2 * NFB_H + NFB_O, 256, 0, stream>>>(
      tb_ih, ntile_ih, tb_hh, ntile_hh, tb_ho, ntile_ho, totals);
  scan_base_kernel<<<3, 256, 0, stream>>>(totals, fbb_ih, fbb_hh, fbb_ho);
  place_kernel<<<ntile_ih + ntile_hh + ntile_ho, 256, 0, stream>>>(
      ih_rows, ih_cols, ih_vals, nnz_ih, tb_ih, ntile_ih, fbb_ih, s_ih,
      hh_rows, hh_cols, hh_vals, nnz_hh, tb_hh, ntile_hh, fbb_hh, s_hh,
      ho_rows, ho_cols, ho_vals, nnz_ho, tb_ho, fbb_ho, s_ho);
  rowcount_kernel<<<2 * NFB_H + NFB_O, 256, 0, stream>>>(
      s_ih, fbb_ih, ih_cur, s_hh, fbb_hh, hh_cur, s_ho, fbb_ho, ho_cur);
  scan_csr_kernel<<<3, 1024, 0, stream>>>(
      ih_cur, Hh, ih_rs, hh_cur, Hh, hh_rs, ho_cur, Oo, ho_rs);
  csort_kernel<<<2 * NFB_H + NFB_O, 256, 0, stream>>>(
      s_ih, fbb_ih, ih_rs, ih_ent,
      s_hh, fbb_hh, hh_rs, hh_ent,
      s_ho, fbb_ho, ho_rs, ho_ent);

  // pre[t][r][b] fp16, XCD-pinned time chunks
  preih_kernel<<<8 * Hh / 4, 256, 0, stream>>>(
      ih_rs, ih_cur, ih_ent, hh_bias, x2h, (__half2*)preAll);

  // Recurrence: one dispatch per step
  for (int t = 0; t < Tt; t++) {
    step_kernel<<<Hh / 4, 256, 0, stream>>>(
        hh_rs, hh_cur, hh_ent,
        preAll + (size_t)t * Hh * Bb,
        hAll + (size_t)t * Hh * Bb,
        hAll + (size_t)(t + 1) * Hh * Bb);
  }

  // Output spmm (XCD t-partitioned) + final transpose
  out_kernel<<<2048, 256, 0, stream>>>(
      ho_rs, ho_cur, ho_ent, ho_bias, hAll, out_tmp);
  transpose_out_kernel<<<Tt * (Oo / 64), 256, 0, stream>>>(out_tmp, out);

  (void)n_in; (void)out_size; (void)ws_size;
}